// Round 3
// baseline (236.776 us; speedup 1.0000x reference)
//
#include <hip/hip_runtime.h>
#include <math.h>

typedef __attribute__((ext_vector_type(8))) short bf16x8;   // 8 bf16 = 4 VGPRs
typedef __attribute__((ext_vector_type(4))) float f32x4;    // MFMA acc

#define NEXP 8
#define BATCH 2048

__device__ __forceinline__ unsigned short f2bf(float f) {
    union { float f; unsigned u; } v; v.f = f;
    unsigned r = v.u + 0x7FFFu + ((v.u >> 16) & 1u);   // RTNE
    return (unsigned short)(r >> 16);
}

// Fused convert: [W0|W1|W2|x] f32 -> contiguous bf16 region at dst.
#define C0 1048576   // NW0/4
#define C1 3145728   // +NW1/4
#define C2 4194304   // +NW2/4
#define C3 4456448   // +NX0/4  (total float4s; 17408 blocks * 256)
__global__ void cvt_all(const float* __restrict__ W0, const float* __restrict__ W1,
                        const float* __restrict__ W2, const float* __restrict__ x,
                        unsigned short* __restrict__ dst) {
    int i = blockIdx.x * blockDim.x + threadIdx.x;
    float4 v;
    if (i < C0)       v = ((const float4*)W0)[i];
    else if (i < C1)  v = ((const float4*)W1)[i - C0];
    else if (i < C2)  v = ((const float4*)W2)[i - C1];
    else              v = ((const float4*)x)[i - C2];
    ushort4 o;
    o.x = f2bf(v.x); o.y = f2bf(v.y); o.z = f2bf(v.z); o.w = f2bf(v.w);
    ((ushort4*)dst)[i] = o;
}

// async global->LDS, 16B per lane; LDS dst is wave-uniform base + lane*16
__device__ __forceinline__ void gload_lds16(const unsigned short* g, void* lds_dst) {
    __builtin_amdgcn_global_load_lds(
        (const __attribute__((address_space(1))) unsigned int*)g,
        (__attribute__((address_space(3))) unsigned int*)lds_dst,
        16, 0, 0);
}

// Blended-expert layer, bf16 MFMA. BM=128, BN=16*NU, BK=32, 512 threads.
// Wave w=(mw=w&1, ew=w>>1): computes m in [64*mw,64*mw+64) x all BN cols for
// experts {2ew, 2ew+1} (separate accumulators, fp32 blend in epilogue).
// LDS staging: xs[128][32] bf16 @0 (8KB) + W[e][BN][32] bf16 @8KB, filled by
// global_load_lds dwordx4 in 1KB chunks (16 rows x 32 cols), 1+NU chunks/wave.
// Epilogue: 2-phase LDS reduce over the 4 expert-pair waves (2 bufs).
template<int NU>
__global__ __launch_bounds__(512, 2) void moe_mfma2(
    const unsigned short* __restrict__ Xb,   // [BATCH, Din] bf16
    const unsigned short* __restrict__ Wb,   // [NEXP, Dout, Din] bf16
    const float* __restrict__ Bias,          // [NEXP, Dout]
    const float* __restrict__ WBl,           // [BATCH, NEXP]
    void* __restrict__ Yout,                 // bf16 or f32 [BATCH, Dout]
    int Din, int Dout, int act, int out_bf16)
{
    constexpr int BN   = 16 * NU;
    constexpr int STAG = 8192 + NEXP * BN * 64;      // staging bytes
    constexpr int PART = 2 * 128 * BN * 4;           // two f32 partial bufs
    constexpr int SMEM = STAG > PART ? STAG : PART;
    __shared__ __align__(16) char smem[SMEM];
    float* lds_f = (float*)smem;

    const int tid = threadIdx.x;
    const int w   = tid >> 6;         // 0..7
    const int l   = tid & 63;
    const int lh  = l >> 4;           // 0..3
    const int ll  = l & 15;           // 0..15
    const int mw  = w & 1;
    const int ew  = w >> 1;           // 0..3
    const int e0  = 2 * ew;
    const int m0  = blockIdx.y * 128;
    const int n0  = blockIdx.x * BN;

    f32x4 acc0[4][NU], acc1[4][NU];
    #pragma unroll
    for (int t = 0; t < 4; ++t)
        #pragma unroll
        for (int u = 0; u < NU; ++u)
            #pragma unroll
            for (int i = 0; i < 4; ++i) { acc0[t][u][i] = 0.f; acc1[t][u][i] = 0.f; }

    // staging: chunk = 1KB = 16 rows x 32 bf16 cols; lane l -> row l>>2, 16B slot l&3
    constexpr int CPW = 1 + NU;                      // chunks per wave (total 8+8*NU)
    const int prow = l >> 2;
    const int pcol = (l & 3) * 8;
    const unsigned short* srcp[CPW];
    #pragma unroll
    for (int j = 0; j < CPW; ++j) {
        const int c = w + 8 * j;
        if (c < 8) {
            srcp[j] = Xb + (size_t)(m0 + 16 * c + prow) * Din + pcol;
        } else {
            const int e = (c - 8) / NU, r = (c - 8) % NU;
            srcp[j] = Wb + ((size_t)e * Dout + n0 + 16 * r + prow) * Din + pcol;
        }
    }

    const char* wb0p = smem + 8192 + e0 * (BN * 64);

    const int nk = Din >> 5;
    for (int kk = 0; kk < nk; ++kk) {
        const int k0 = kk << 5;
        __syncthreads();                              // prev step's frag reads done
        #pragma unroll
        for (int j = 0; j < CPW; ++j)
            gload_lds16(srcp[j] + k0, smem + (w + 8 * j) * 1024);
        __syncthreads();                              // drain -> tiles visible

        bf16x8 a[4];
        #pragma unroll
        for (int t = 0; t < 4; ++t)
            a[t] = *(const bf16x8*)(smem + (64 * mw + 16 * t + ll) * 64 + lh * 16);
        #pragma unroll
        for (int u = 0; u < NU; ++u) {
            bf16x8 b0 = *(const bf16x8*)(wb0p + (16 * u + ll) * 64 + lh * 16);
            bf16x8 b1 = *(const bf16x8*)(wb0p + BN * 64 + (16 * u + ll) * 64 + lh * 16);
            #pragma unroll
            for (int t = 0; t < 4; ++t) {
                acc0[t][u] = __builtin_amdgcn_mfma_f32_16x16x32_bf16(a[t], b0, acc0[t][u], 0, 0, 0);
                acc1[t][u] = __builtin_amdgcn_mfma_f32_16x16x32_bf16(a[t], b1, acc1[t][u], 0, 0, 0);
            }
        }
    }
    __syncthreads();   // all frag reads done before partials overwrite staging

    // blended bias for this wave's experts
    float b0v[NU], b1v[NU];
    #pragma unroll
    for (int u = 0; u < NU; ++u) {
        const int n = n0 + u * 16 + ll;
        b0v[u] = Bias[(size_t)e0 * Dout + n];
        b1v[u] = Bias[(size_t)(e0 + 1) * Dout + n];
    }

    // C/D layout: reg r of lane -> C[16t+4*lh+r][16u+ll]  (m89-verified)
    float* buf = lds_f + (ew >> 1) * (128 * BN);
    if (!(ew & 1)) {    // P1: ew in {0,2} write
        #pragma unroll
        for (int t = 0; t < 4; ++t) {
            #pragma unroll
            for (int r = 0; r < 4; ++r) {
                const int m = 64 * mw + 16 * t + 4 * lh + r;
                float2 wbp = ((const float2*)(WBl + (size_t)(m0 + m) * NEXP))[ew];
                #pragma unroll
                for (int u = 0; u < NU; ++u)
                    buf[m * BN + u * 16 + ll] =
                        wbp.x * (acc0[t][u][r] + b0v[u]) + wbp.y * (acc1[t][u][r] + b1v[u]);
            }
        }
    }
    __syncthreads();
    if (ew & 1) {       // P2: ew in {1,3} accumulate
        #pragma unroll
        for (int t = 0; t < 4; ++t) {
            #pragma unroll
            for (int r = 0; r < 4; ++r) {
                const int m = 64 * mw + 16 * t + 4 * lh + r;
                float2 wbp = ((const float2*)(WBl + (size_t)(m0 + m) * NEXP))[ew];
                #pragma unroll
                for (int u = 0; u < NU; ++u)
                    buf[m * BN + u * 16 + ll] +=
                        wbp.x * (acc0[t][u][r] + b0v[u]) + wbp.y * (acc1[t][u][r] + b1v[u]);
            }
        }
    }
    __syncthreads();

    // P3: sum the two bufs, activation, store
    constexpr int TPR = 4 * NU;          // threads per row (16B each)
    constexpr int RPP = 512 / TPR;       // rows per pass
    const int r0 = tid / TPR;
    const int c4 = (tid % TPR) * 4;
    #pragma unroll
    for (int i = 0; i < 128 / RPP; ++i) {
        const int m = r0 + RPP * i;
        float4 s = *(const float4*)(lds_f + m * BN + c4);
        float4 q = *(const float4*)(lds_f + 128 * BN + m * BN + c4);
        s.x += q.x; s.y += q.y; s.z += q.z; s.w += q.w;
        if (act) {
            s.x = s.x > 0.f ? s.x : expm1f(s.x);
            s.y = s.y > 0.f ? s.y : expm1f(s.y);
            s.z = s.z > 0.f ? s.z : expm1f(s.z);
            s.w = s.w > 0.f ? s.w : expm1f(s.w);
        }
        const size_t off = (size_t)(m0 + m) * Dout + n0 + c4;
        if (out_bf16) {
            ushort4 o;
            o.x = f2bf(s.x); o.y = f2bf(s.y); o.z = f2bf(s.z); o.w = f2bf(s.w);
            *(ushort4*)((unsigned short*)Yout + off) = o;
        } else {
            *(float4*)((float*)Yout + off) = s;
        }
    }
}

// ---------------- fp32 fallback for small ws_size ----------------
#define BM 64
#define BNF 64
#define BKF 16
#define PAD 4

__global__ __launch_bounds__(256) void moe_layer_f32(
    const float* __restrict__ X, const float* __restrict__ W,
    const float* __restrict__ Bias, const float* __restrict__ WB,
    float* __restrict__ Y, int Din, int Dout, int act)
{
    __shared__ float As[BKF][BM + PAD];
    __shared__ float Bs[BKF][BNF + PAD];
    const int tid = threadIdx.x;
    const int tm = tid >> 4, tn = tid & 15;
    const int m0 = blockIdx.y * BM, n0 = blockIdx.x * BNF;
    const int lr = tid >> 2, lc = (tid & 3) << 2;
    float acc[4][4] = {};
    const float* xrow  = X  + (size_t)(m0 + lr) * Din;
    const float* wbrow = WB + (size_t)(m0 + lr) * NEXP;
    const float* wrow0 = W  + (size_t)(n0 + lr) * Din;
    for (int e = 0; e < NEXP; ++e) {
        const float wbe = wbrow[e];
        const float* wrow = wrow0 + (size_t)e * Dout * Din;
        for (int k0 = 0; k0 < Din; k0 += BKF) {
            float4 av = *(const float4*)(xrow + k0 + lc);
            float4 bv = *(const float4*)(wrow + k0 + lc);
            __syncthreads();
            As[lc+0][lr] = av.x*wbe; As[lc+1][lr] = av.y*wbe;
            As[lc+2][lr] = av.z*wbe; As[lc+3][lr] = av.w*wbe;
            Bs[lc+0][lr] = bv.x; Bs[lc+1][lr] = bv.y;
            Bs[lc+2][lr] = bv.z; Bs[lc+3][lr] = bv.w;
            __syncthreads();
            #pragma unroll
            for (int k = 0; k < BKF; ++k) {
                float4 a = *(const float4*)&As[k][tm << 2];
                float4 b = *(const float4*)&Bs[k][tn << 2];
                acc[0][0]+=a.x*b.x; acc[0][1]+=a.x*b.y; acc[0][2]+=a.x*b.z; acc[0][3]+=a.x*b.w;
                acc[1][0]+=a.y*b.x; acc[1][1]+=a.y*b.y; acc[1][2]+=a.y*b.z; acc[1][3]+=a.y*b.w;
                acc[2][0]+=a.z*b.x; acc[2][1]+=a.z*b.y; acc[2][2]+=a.z*b.z; acc[2][3]+=a.z*b.w;
                acc[3][0]+=a.w*b.x; acc[3][1]+=a.w*b.y; acc[3][2]+=a.w*b.z; acc[3][3]+=a.w*b.w;
            }
        }
    }
    #pragma unroll
    for (int im = 0; im < 4; ++im) {
        const int m = m0 + (tm << 2) + im;
        const float* wbm = WB + (size_t)m * NEXP;
        float wv[NEXP];
        #pragma unroll
        for (int e = 0; e < NEXP; ++e) wv[e] = wbm[e];
        #pragma unroll
        for (int in = 0; in < 4; ++in) {
            const int n = n0 + (tn << 2) + in;
            float bsum = 0.f;
            #pragma unroll
            for (int e = 0; e < NEXP; ++e) bsum += wv[e] * Bias[(size_t)e * Dout + n];
            float v = acc[im][in] + bsum;
            if (act) v = v > 0.f ? v : expm1f(v);
            acc[im][in] = v;
        }
        float4 o = make_float4(acc[im][0], acc[im][1], acc[im][2], acc[im][3]);
        *(float4*)(Y + (size_t)m * Dout + n0 + (tn << 2)) = o;
    }
}

extern "C" void kernel_launch(void* const* d_in, const int* in_sizes, int n_in,
                              void* d_out, int out_size, void* d_ws, size_t ws_size,
                              hipStream_t stream)
{
    (void)in_sizes; (void)n_in; (void)out_size;
    const float* wb = (const float*)d_in[0];
    const float* x  = (const float*)d_in[1];
    const float* W0 = (const float*)d_in[2];
    const float* B0 = (const float*)d_in[3];
    const float* W1 = (const float*)d_in[4];
    const float* B1 = (const float*)d_in[5];
    const float* W2 = (const float*)d_in[6];
    const float* B2 = (const float*)d_in[7];
    float* out = (float*)d_out;

    const size_t NW0 = (size_t)8*1024*512, NW1 = (size_t)8*1024*1024, NW2 = (size_t)8*512*1024;
    const size_t NX0 = (size_t)BATCH*512, NX1 = (size_t)BATCH*1024;
    const size_t need = (NW0 + NW1 + NW2 + NX0 + 2 * NX1) * 2;   // ~44 MB bf16

    if (ws_size >= need) {
        unsigned short* Wb0 = (unsigned short*)d_ws;
        unsigned short* Wb1 = Wb0 + NW0;
        unsigned short* Wb2 = Wb1 + NW1;
        unsigned short* xb0 = Wb2 + NW2;
        unsigned short* xb1 = xb0 + NX0;
        unsigned short* xb2 = xb1 + NX1;
        cvt_all<<<C3 / 256, 256, 0, stream>>>(W0, W1, W2, x, Wb0);
        moe_mfma2<4><<<dim3(16, 16), 512, 0, stream>>>(xb0, Wb0, B0, wb, xb1, 512,  1024, 1, 1);
        moe_mfma2<4><<<dim3(16, 16), 512, 0, stream>>>(xb1, Wb1, B1, wb, xb2, 1024, 1024, 1, 1);
        moe_mfma2<2><<<dim3(16, 16), 512, 0, stream>>>(xb2, Wb2, B2, wb, out, 1024, 512,  0, 0);
    } else {
        float* x1 = (float*)d_ws;
        float* x2 = x1 + (size_t)BATCH * 1024;
        moe_layer_f32<<<dim3(1024/BNF, BATCH/BM), 256, 0, stream>>>(x,  W0, B0, wb, x1, 512,  1024, 1);
        moe_layer_f32<<<dim3(1024/BNF, BATCH/BM), 256, 0, stream>>>(x1, W1, B1, wb, x2, 1024, 1024, 1);
        moe_layer_f32<<<dim3(512/BNF,  BATCH/BM), 256, 0, stream>>>(x2, W2, B2, wb, out, 1024, 512,  0);
    }
}